// Round 1
// baseline (59.480 us; speedup 1.0000x reference)
//
#include <hip/hip_runtime.h>

#define SEQ_N 131072
#define TPB   256
#define NB    128
#define KROWS 4   // NB * TPB * KROWS == SEQ_N

#define FINF __builtin_inff()

// Matrix stored as columns: col[c][r] = M[r][c] (min-plus 3x3).
// State update: new = M ⊗ old.

__device__ __forceinline__ void apply_step(float col[3][3], float c0, float c1,
                                           float c2, bool mask0, bool mask2) {
#pragma unroll
    for (int c = 0; c < 3; ++c) {
        float p0 = col[c][0], p1 = col[c][1], p2 = col[c][2];
        float n0 = c0 + fminf(p0, p1);
        if (mask0) n0 = FINF;                       // row i==1: j=i-1 invalid
        float n1 = c1 + fminf(n0, fminf(p1, p2));
        float n2 = c2 + fminf(n1, p2);
        if (mask2) n2 = FINF;                       // row i==N: j=i+1 invalid
        col[c][0] = n0; col[c][1] = n1; col[c][2] = n2;
    }
}

// C = B ⊗ A  (A covers earlier rows, B later).  (B⊗A)[r][c] = min_k B[r][k]+A[k][c]
__device__ __forceinline__ void combine(const float B[3][3], const float A[3][3],
                                        float C[3][3]) {
#pragma unroll
    for (int c = 0; c < 3; ++c) {
#pragma unroll
        for (int r = 0; r < 3; ++r) {
            C[c][r] = fminf(fminf(B[0][r] + A[c][0], B[1][r] + A[c][1]),
                            B[2][r] + A[c][2]);
        }
    }
}

// Ordered (non-commutative) tree reduce of `cnt` matrices held in lds[0..cnt-1].
template <int CNT>
__device__ __forceinline__ void lds_tree_reduce(float (*lds)[9], int tid) {
    int cnt = CNT;
    while (cnt > 1) {
        __syncthreads();
        const int half = cnt >> 1;
        float A[3][3], B[3][3], C[3][3];
        if (tid < half) {
#pragma unroll
            for (int c = 0; c < 3; ++c)
#pragma unroll
                for (int r = 0; r < 3; ++r) {
                    A[c][r] = lds[2 * tid][c * 3 + r];
                    B[c][r] = lds[2 * tid + 1][c * 3 + r];
                }
            combine(B, A, C);
        }
        __syncthreads();
        if (tid < half) {
#pragma unroll
            for (int c = 0; c < 3; ++c)
#pragma unroll
                for (int r = 0; r < 3; ++r)
                    lds[tid][c * 3 + r] = C[c][r];
        }
        cnt = half;
    }
}

__global__ __launch_bounds__(TPB) void dtw_stage1(const float* __restrict__ o,
                                                  const float* __restrict__ t,
                                                  float* __restrict__ ws) {
    const int tid  = threadIdx.x;
    const int g    = blockIdx.x * TPB + tid;
    const int base = g * KROWS;      // rows base+1 .. base+KROWS (1-indexed i)

    const float4 ov = *reinterpret_cast<const float4*>(o + base);
    const float4 tv = *reinterpret_cast<const float4*>(t + base);
    const float tlo = (base >= 1) ? t[base - 1] : 0.0f;               // masked if unused
    const float thi = (base + KROWS < SEQ_N) ? t[base + KROWS] : 0.0f; // masked if unused

    // init identity (min-plus): diag 0, off-diag INF
    float col[3][3];
#pragma unroll
    for (int c = 0; c < 3; ++c)
#pragma unroll
        for (int r = 0; r < 3; ++r)
            col[c][r] = (c == r) ? 0.0f : FINF;

    const bool firstRow = (base == 0);              // contains i == 1
    const bool lastRow  = (base + KROWS == SEQ_N);  // contains i == N

    // step i = base+1..base+4; c0=|o-t[i-2]|, c1=|o-t[i-1]|, c2=|o-t[i]|
    apply_step(col, fabsf(ov.x - tlo),  fabsf(ov.x - tv.x), fabsf(ov.x - tv.y), firstRow, false);
    apply_step(col, fabsf(ov.y - tv.x), fabsf(ov.y - tv.y), fabsf(ov.y - tv.z), false,    false);
    apply_step(col, fabsf(ov.z - tv.y), fabsf(ov.z - tv.z), fabsf(ov.z - tv.w), false,    false);
    apply_step(col, fabsf(ov.w - tv.z), fabsf(ov.w - tv.w), fabsf(ov.w - thi),  false,    lastRow);

    __shared__ float lds[TPB][9];
#pragma unroll
    for (int c = 0; c < 3; ++c)
#pragma unroll
        for (int r = 0; r < 3; ++r)
            lds[tid][c * 3 + r] = col[c][r];

    lds_tree_reduce<TPB>(lds, tid);

    if (tid == 0) {
        float* wsm = ws + blockIdx.x * 9;
#pragma unroll
        for (int k = 0; k < 9; ++k) wsm[k] = lds[0][k];
    }
}

__global__ __launch_bounds__(NB) void dtw_stage2(const float* __restrict__ ws,
                                                 float* __restrict__ dout) {
    const int tid = threadIdx.x;
    __shared__ float lds[NB][9];
#pragma unroll
    for (int k = 0; k < 9; ++k) lds[tid][k] = ws[tid * 9 + k];

    lds_tree_reduce<NB>(lds, tid);

    if (tid == 0) {
        // result = M_total ⊗ v0, v0 = (INF, 0, INF)  →  v[r] = M[r][1];
        // output = v[1] = M[1][1] = col 1, row 1 = lds[0][1*3+1]
        dout[0] = lds[0][4];
    }
}

extern "C" void kernel_launch(void* const* d_in, const int* in_sizes, int n_in,
                              void* d_out, int out_size, void* d_ws, size_t ws_size,
                              hipStream_t stream) {
    const float* o = (const float*)d_in[0];   // output
    const float* t = (const float*)d_in[1];   // target
    float* ws = (float*)d_ws;                 // NB * 9 floats = 4608 B

    dtw_stage1<<<NB, TPB, 0, stream>>>(o, t, ws);
    dtw_stage2<<<1, NB, 0, stream>>>(ws, (float*)d_out);
}